// Round 1
// baseline (273.201 us; speedup 1.0000x reference)
//
#include <hip/hip_runtime.h>

#define BT     16
#define C_IN   32
#define C_OUT  32
#define NRAND  16
#define NNODES 32768   // 32*32*32

// ---------------------------------------------------------------------------
// Transpose x (b, c, m) -> xT (b, m, c), fp32, LDS-tiled 32x64.
// ---------------------------------------------------------------------------
__global__ __launch_bounds__(256) void transpose_x_kernel(
    const float* __restrict__ x, float* __restrict__ xT) {
    __shared__ float tile[C_IN][64 + 1];   // +1 pad: conflict-free column reads
    const int b     = blockIdx.y;
    const int mbase = blockIdx.x * 64;
    const int tid   = threadIdx.x;

    #pragma unroll
    for (int i = 0; i < 8; ++i) {
        int lin = tid + i * 256;
        int c   = lin >> 6;     // 0..31
        int m0  = lin & 63;     // 0..63
        tile[c][m0] = x[((size_t)b * C_IN + c) * NNODES + mbase + m0];
    }
    __syncthreads();
    #pragma unroll
    for (int i = 0; i < 8; ++i) {
        int lin = tid + i * 256;
        int m0  = lin >> 5;     // 0..63
        int c   = lin & 31;     // 0..31
        xT[((size_t)b * NNODES + mbase + m0) * C_IN + c] = tile[c][m0];
    }
}

// ---------------------------------------------------------------------------
// Transpose weight (o, c, r) -> w2 (c, r, o)  (tiny: 16384 elements)
// ---------------------------------------------------------------------------
__global__ __launch_bounds__(256) void transpose_w_kernel(
    const float* __restrict__ w, float* __restrict__ w2) {
    int i = blockIdx.x * 256 + threadIdx.x;   // destination index
    if (i < C_IN * NRAND * C_OUT) {
        int o = i & 31;
        int r = (i >> 5) & 15;
        int c = i >> 9;
        w2[i] = w[((size_t)o * C_IN + c) * NRAND + r];
    }
}

// ---------------------------------------------------------------------------
// Main: one thread per (b, n). 32 fp32 accumulators over o.
// Weight accesses are loop-uniform -> scalar loads -> v_fmac_f32 v,s,v.
// TRANSPOSED: xsrc = xT (b,m,c), wsrc = w2 (c,r,o)
// else:       xsrc = x  (b,c,m), wsrc = w  (o,c,r)   [ws-too-small fallback]
// ---------------------------------------------------------------------------
template <bool TRANSPOSED>
__global__ __launch_bounds__(256) void mixer_kernel(
    const float* __restrict__ xsrc,
    const float* __restrict__ wsrc,
    const float* __restrict__ bias,
    const int*   __restrict__ idx,
    float*       __restrict__ out) {
    const int b = blockIdx.y;
    const int n = blockIdx.x * 256 + threadIdx.x;

    float acc[C_OUT];
    #pragma unroll
    for (int o = 0; o < C_OUT; ++o) acc[o] = bias[o];

    // 16 neighbor indices for this node: 64 contiguous bytes
    int mlist[NRAND];
    {
        const int4* idxp = reinterpret_cast<const int4*>(idx) + (size_t)n * 4;
        #pragma unroll
        for (int q = 0; q < 4; ++q) {
            int4 iv = idxp[q];
            mlist[q * 4 + 0] = iv.x;
            mlist[q * 4 + 1] = iv.y;
            mlist[q * 4 + 2] = iv.z;
            mlist[q * 4 + 3] = iv.w;
        }
    }

    #pragma unroll 1
    for (int r = 0; r < NRAND; ++r) {
        const int m = mlist[r];
        if (TRANSPOSED) {
            const float4* xp = reinterpret_cast<const float4*>(
                xsrc + ((size_t)b * NNODES + m) * C_IN);
            float4 xv[8];
            #pragma unroll
            for (int c4 = 0; c4 < 8; ++c4) xv[c4] = xp[c4];   // 128 B gather
            #pragma unroll
            for (int c4 = 0; c4 < 8; ++c4) {
                #pragma unroll
                for (int j = 0; j < 4; ++j) {
                    const int   c  = c4 * 4 + j;
                    const float xs = (j == 0) ? xv[c4].x
                                   : (j == 1) ? xv[c4].y
                                   : (j == 2) ? xv[c4].z
                                              : xv[c4].w;
                    const float* wrow = wsrc + ((size_t)c * NRAND + r) * C_OUT;
                    #pragma unroll
                    for (int o = 0; o < C_OUT; ++o)
                        acc[o] += wrow[o] * xs;   // wrow[o] wave-uniform -> SGPR
                }
            }
        } else {
            #pragma unroll
            for (int c = 0; c < C_IN; ++c) {
                const float xs = xsrc[((size_t)b * C_IN + c) * NNODES + m];
                #pragma unroll
                for (int o = 0; o < C_OUT; ++o)
                    acc[o] += wsrc[((size_t)o * C_IN + c) * NRAND + r] * xs;
            }
        }
    }

    #pragma unroll
    for (int o = 0; o < C_OUT; ++o)
        out[((size_t)b * C_OUT + o) * NNODES + n] = acc[o];   // coalesced per o
}

// ---------------------------------------------------------------------------
extern "C" void kernel_launch(void* const* d_in, const int* in_sizes, int n_in,
                              void* d_out, int out_size, void* d_ws, size_t ws_size,
                              hipStream_t stream) {
    const float* x    = (const float*)d_in[0];
    const float* w    = (const float*)d_in[1];
    const float* bias = (const float*)d_in[2];
    const int*   idx  = (const int*)d_in[3];
    float*       out  = (float*)d_out;

    const size_t xT_bytes = (size_t)BT * NNODES * C_IN * sizeof(float);   // 64 MiB
    const size_t w2_bytes = (size_t)C_IN * NRAND * C_OUT * sizeof(float); // 64 KiB

    if (ws_size >= xT_bytes + w2_bytes) {
        float* xT = (float*)d_ws;
        float* w2 = (float*)((char*)d_ws + xT_bytes);

        dim3 tg(NNODES / 64, BT);
        transpose_x_kernel<<<tg, 256, 0, stream>>>(x, xT);
        transpose_w_kernel<<<(C_IN * NRAND * C_OUT + 255) / 256, 256, 0, stream>>>(w, w2);

        dim3 g(NNODES / 256, BT);
        mixer_kernel<true><<<g, 256, 0, stream>>>(xT, w2, bias, idx, out);
    } else {
        dim3 g(NNODES / 256, BT);
        mixer_kernel<false><<<g, 256, 0, stream>>>(x, w, bias, idx, out);
    }
}

// Round 2
// 79.354 us; speedup vs baseline: 3.4428x; 3.4428x over previous
//
#include <hip/hip_runtime.h>
#include <hip/hip_bf16.h>

#define BT     16
#define C_IN   32
#define C_OUT  32
#define NRAND  16
#define NNODES 32768   // 32*32*32

typedef __attribute__((ext_vector_type(8))) short bf16x8;   // 8 bf16 = 4 VGPRs
typedef __attribute__((ext_vector_type(4))) float f32x4;

__device__ inline unsigned short f2bf(float f) {
    __hip_bfloat16 h = __float2bfloat16(f);
    return __builtin_bit_cast(unsigned short, h);
}

// ---------------------------------------------------------------------------
// x (b,c,m) fp32  ->  xT (b,m,c) bf16.   One node-vector = 32 bf16 = 64 B.
// ---------------------------------------------------------------------------
__global__ __launch_bounds__(256) void build_xt_bf16(
    const float* __restrict__ x, unsigned short* __restrict__ xT) {
    __shared__ float tile[C_IN][65];          // +1 pad: conflict-free col reads
    const int b     = blockIdx.y;
    const int mbase = blockIdx.x * 64;
    const int tid   = threadIdx.x;

    #pragma unroll
    for (int i = 0; i < 2; ++i) {             // 512 float4 reads
        int lin = tid + i * 256;
        int c   = lin >> 4;                   // 0..31
        int mg  = lin & 15;                   // 0..15 (x4 nodes)
        float4 v = *reinterpret_cast<const float4*>(
            &x[((size_t)b * C_IN + c) * NNODES + mbase + mg * 4]);
        tile[c][mg * 4 + 0] = v.x;
        tile[c][mg * 4 + 1] = v.y;
        tile[c][mg * 4 + 2] = v.z;
        tile[c][mg * 4 + 3] = v.w;
    }
    __syncthreads();
    #pragma unroll
    for (int i = 0; i < 2; ++i) {             // 512 ushort4 writes (8 B, c-contig)
        int lin = tid + i * 256;
        int m0  = lin >> 3;                   // 0..63
        int cg  = lin & 7;                    // 0..7 (x4 channels)
        ushort4 u;
        u.x = f2bf(tile[cg * 4 + 0][m0]);
        u.y = f2bf(tile[cg * 4 + 1][m0]);
        u.z = f2bf(tile[cg * 4 + 2][m0]);
        u.w = f2bf(tile[cg * 4 + 3][m0]);
        *reinterpret_cast<ushort4*>(
            &xT[(((size_t)b << 15) + mbase + m0) * C_IN + cg * 4]) = u;
    }
}

// ---------------------------------------------------------------------------
// W (o,c,r) fp32 -> Wp bf16 in MFMA A-frag order:
//   Wp[(((h*16 + r)*4 + g)*16 + row)*8 + e] = W[o=h*16+row][c=g*8+e][r]
// so lane l reading frag(h,r) gets its 16 B at Wp + frag_base + l*16B.
// ---------------------------------------------------------------------------
__global__ __launch_bounds__(256) void build_w_bf16(
    const float* __restrict__ w, unsigned short* __restrict__ Wp) {
    int i = blockIdx.x * 256 + threadIdx.x;   // 16384
    int e   = i & 7;
    int row = (i >> 3) & 15;
    int g   = (i >> 7) & 3;
    int r   = (i >> 9) & 15;
    int h   = i >> 13;
    int o = h * 16 + row;
    int c = g * 8 + e;
    Wp[i] = f2bf(w[((size_t)o * C_IN + c) * NRAND + r]);
}

// ---------------------------------------------------------------------------
// Main MFMA kernel. Block = 256 thr = 4 waves. Each wave: 4 tiles of
// (32 o x 16 n), K = 512 = 16 r x 32 c -> 32 MFMAs/tile.
// B-operand gathered straight from global xT (16 B/lane), A from LDS W.
// Batch pinned to XCD via blockIdx swizzle (b slice = 2 MiB, fits XCD L2).
// ---------------------------------------------------------------------------
__global__ __launch_bounds__(256) void mixer_mfma(
    const unsigned short* __restrict__ xT,
    const unsigned short* __restrict__ Wp,
    const float* __restrict__ bias,
    const int*   __restrict__ idx,
    float*       __restrict__ out) {
    __shared__ unsigned short wlds[2 * NRAND * 4 * 16 * 8];   // 32 KiB
    {
        const uint4* src = reinterpret_cast<const uint4*>(Wp);
        uint4*       dst = reinterpret_cast<uint4*>(wlds);
        #pragma unroll
        for (int i = 0; i < 8; ++i)
            dst[threadIdx.x + i * 256] = src[threadIdx.x + i * 256];
    }
    __syncthreads();

    // blockIdx -> (xcd, batch, chunk): each XCD runs its 2 batches SEQUENTIALLY
    const int bid   = blockIdx.x;             // 0..2047
    const int xcd   = bid & 7;
    const int jj    = bid >> 3;               // 0..255
    const int b     = xcd * 2 + (jj >> 7);    // first 128 blocks -> batch 2*xcd
    const int chunk = jj & 127;               // 256-node chunk

    const int wave = threadIdx.x >> 6;
    const int lane = threadIdx.x & 63;
    const int row  = lane & 15;               // n-offset within tile / A-row
    const int g    = lane >> 4;               // lane-group: c-chunk g*8..g*8+7

    const bf16x8* wfrag = reinterpret_cast<const bf16x8*>(wlds);
    const float4  bv0   = reinterpret_cast<const float4*>(bias)[g];
    const float4  bv1   = reinterpret_cast<const float4*>(bias)[g + 4];
    const unsigned short* xb = xT + ((size_t)b << 20);        // b*32768*32

    #pragma unroll 1
    for (int t = 0; t < 4; ++t) {
        const int n0 = chunk * 256 + wave * 64 + t * 16;

        // idx rows for this tile's 16 nodes (all 4 lane-groups need all 16 r)
        const int4* ip = reinterpret_cast<const int4*>(idx) + (size_t)(n0 + row) * 4;

        // gather B-fragments: 16 B per lane per r, straight into registers
        bf16x8 bf[NRAND];
        #pragma unroll
        for (int q = 0; q < 4; ++q) {
            const int4 iv = ip[q];
            bf[q * 4 + 0] = *reinterpret_cast<const bf16x8*>(xb + (((size_t)iv.x) << 5) + (g << 3));
            bf[q * 4 + 1] = *reinterpret_cast<const bf16x8*>(xb + (((size_t)iv.y) << 5) + (g << 3));
            bf[q * 4 + 2] = *reinterpret_cast<const bf16x8*>(xb + (((size_t)iv.z) << 5) + (g << 3));
            bf[q * 4 + 3] = *reinterpret_cast<const bf16x8*>(xb + (((size_t)iv.w) << 5) + (g << 3));
        }

        f32x4 c0 = {bv0.x, bv0.y, bv0.z, bv0.w};
        f32x4 c1 = {bv1.x, bv1.y, bv1.z, bv1.w};
        #pragma unroll
        for (int r = 0; r < NRAND; ++r) {
            c0 = __builtin_amdgcn_mfma_f32_16x16x32_bf16(
                     wfrag[(r * 4 + g) * 16 + row], bf[r], c0, 0, 0, 0);
            c1 = __builtin_amdgcn_mfma_f32_16x16x32_bf16(
                     wfrag[((NRAND + r) * 4 + g) * 16 + row], bf[r], c1, 0, 0, 0);
        }

        // C/D layout (HW-verified): col = lane&15 -> n, row = g*4+reg -> o
        float* ob = out + (((size_t)b * C_OUT) << 15) + n0 + row;
        #pragma unroll
        for (int jr = 0; jr < 4; ++jr) {
            __builtin_nontemporal_store(c0[jr], ob + (((size_t)(g * 4 + jr)) << 15));
            __builtin_nontemporal_store(c1[jr], ob + (((size_t)(g * 4 + jr + 16)) << 15));
        }
    }
}

// ---------------------------------------------------------------------------
// fp32 fallback (ws too small) — round-0 kernel, known-correct.
// ---------------------------------------------------------------------------
__global__ __launch_bounds__(256) void mixer_fallback(
    const float* __restrict__ xsrc, const float* __restrict__ wsrc,
    const float* __restrict__ bias, const int* __restrict__ idx,
    float* __restrict__ out) {
    const int b = blockIdx.y;
    const int n = blockIdx.x * 256 + threadIdx.x;
    float acc[C_OUT];
    #pragma unroll
    for (int o = 0; o < C_OUT; ++o) acc[o] = bias[o];
    #pragma unroll 1
    for (int r = 0; r < NRAND; ++r) {
        const int m = idx[(size_t)n * NRAND + r];
        #pragma unroll
        for (int c = 0; c < C_IN; ++c) {
            const float xs = xsrc[((size_t)b * C_IN + c) * NNODES + m];
            #pragma unroll
            for (int o = 0; o < C_OUT; ++o)
                acc[o] += wsrc[((size_t)o * C_IN + c) * NRAND + r] * xs;
        }
    }
    #pragma unroll
    for (int o = 0; o < C_OUT; ++o)
        out[((size_t)b * C_OUT + o) * NNODES + n] = acc[o];
}

// ---------------------------------------------------------------------------
extern "C" void kernel_launch(void* const* d_in, const int* in_sizes, int n_in,
                              void* d_out, int out_size, void* d_ws, size_t ws_size,
                              hipStream_t stream) {
    const float* x    = (const float*)d_in[0];
    const float* w    = (const float*)d_in[1];
    const float* bias = (const float*)d_in[2];
    const int*   idx  = (const int*)d_in[3];
    float*       out  = (float*)d_out;

    const size_t xT_bytes = (size_t)BT * NNODES * C_IN * sizeof(unsigned short); // 32 MiB
    const size_t wp_bytes = (size_t)2 * NRAND * 4 * 16 * 8 * sizeof(unsigned short); // 32 KiB

    if (ws_size >= xT_bytes + wp_bytes) {
        unsigned short* xT = (unsigned short*)d_ws;
        unsigned short* Wp = (unsigned short*)((char*)d_ws + xT_bytes);

        dim3 tg(NNODES / 64, BT);
        build_xt_bf16<<<tg, 256, 0, stream>>>(x, xT);
        build_w_bf16<<<(2 * NRAND * 4 * 16 * 8) / 256, 256, 0, stream>>>(w, Wp);

        mixer_mfma<<<BT * (NNODES / 256), 256, 0, stream>>>(xT, Wp, bias, idx, out);
    } else {
        dim3 g(NNODES / 256, BT);
        mixer_fallback<<<g, 256, 0, stream>>>(x, w, bias, idx, out);
    }
}